// Round 10
// baseline (30066.653 us; speedup 1.0000x reference)
//
#include <hip/hip_runtime.h>
#include <cstdint>
#include <cstddef>

typedef _Float16 f16;
typedef _Float16 f16x8 __attribute__((ext_vector_type(8)));
typedef float f32x4 __attribute__((ext_vector_type(4)));
typedef unsigned u32x2 __attribute__((ext_vector_type(2)));

#define T_LEN 1200
#define NB 32
#define HD 384

__device__ __forceinline__ float sigf(float x) { return 1.f / (1.f + __expf(-x)); }
__device__ __forceinline__ float tanhf_s(float x) {
    float ax = fabsf(x);
    float e = __expf(-2.f * ax);
    float r = (1.f - e) / (1.f + e);
    return copysignf(r, x);
}
__device__ __forceinline__ float siluf(float x) { return x * sigf(x); }

// Fast wire: sc0 = L1-bypass, served by the XCD-local L2 (coherent only
// within one XCD). 8B accesses are single-copy atomic.
__device__ __forceinline__ void st_pkt2_l2(unsigned* p, u32x2 a, u32x2 b) {
    asm volatile("global_store_dwordx2 %0, %1, off sc0\n\t"
                 "global_store_dwordx2 %0, %2, off offset:8 sc0"
                 :: "v"(p), "v"(a), "v"(b) : "memory");
}
__device__ __forceinline__ void ld_pkt2_l2(const unsigned* p, u32x2& a, u32x2& b) {
    asm volatile("global_load_dwordx2 %0, %2, off sc0\n\t"
                 "global_load_dwordx2 %1, %2, off offset:8 sc0\n\t"
                 "s_waitcnt vmcnt(0)"
                 : "=&v"(a), "=&v"(b) : "v"(p) : "memory");
}
// Backup wire: sc0 sc1 = full bypass to L3 (device-wide visible) - r6-proven.
__device__ __forceinline__ void st_pkt2_sys(unsigned* p, u32x2 a, u32x2 b) {
    asm volatile("global_store_dwordx2 %0, %1, off sc0 sc1\n\t"
                 "global_store_dwordx2 %0, %2, off offset:8 sc0 sc1"
                 :: "v"(p), "v"(a), "v"(b) : "memory");
}
__device__ __forceinline__ void ld_pkt2_sys(const unsigned* p, u32x2& a, u32x2& b) {
    asm volatile("global_load_dwordx2 %0, %2, off sc0 sc1\n\t"
                 "global_load_dwordx2 %1, %2, off offset:8 sc0 sc1\n\t"
                 "s_waitcnt vmcnt(0)"
                 : "=&v"(a), "=&v"(b) : "v"(p) : "memory");
}

// ---------------- small conversion kernels ----------------
__global__ void k_cvt(const float* __restrict__ src, f16* __restrict__ dst, int n) {
    int i = blockIdx.x * 256 + threadIdx.x;
    if (i < n) dst[i] = (f16)src[i];
}

__global__ void k_w3p(const float* __restrict__ w3, f16* __restrict__ dst) {
    int i = blockIdx.x * 256 + threadIdx.x; // 384*320
    if (i >= 384 * 320) return;
    int c = i / 320, k = i % 320;
    dst[i] = (f16)((k < 304) ? w3[c * 304 + k] : 0.f);
}

// ---------------- conv1 + conv2 fused (f32 out) ----------------
__global__ __launch_bounds__(512) void k_conv12(const float* __restrict__ x,
    const float* __restrict__ w1, const float* __restrict__ b1,
    const float* __restrict__ w2, const float* __restrict__ b2,
    float* __restrict__ c2) {
    const int tid = threadIdx.x;
    const int n = blockIdx.y;
    const int t0 = blockIdx.x * 512;
    __shared__ float xs[520];
    __shared__ float c1s[4][520];
    __shared__ float ws1[20], wb1[4], ws2[320], wb2[16];
    if (tid < 20) ws1[tid] = w1[tid];
    if (tid < 4) wb1[tid] = b1[tid];
    if (tid < 320) ws2[tid] = w2[tid];
    if (tid < 16) wb2[tid] = b2[tid];
    for (int q = tid; q < 520; q += 512) {
        int xi = t0 - 4 + q;
        xs[q] = (xi >= 0 && xi < 6000) ? x[(size_t)n * 6000 + xi] : 0.f;
    }
    __syncthreads();
    for (int p = tid; p < 516; p += 512) {
        int gp = t0 - 2 + p;
#pragma unroll
        for (int ch = 0; ch < 4; ++ch) {
            float a = wb1[ch];
#pragma unroll
            for (int j = 0; j < 5; ++j) a += ws1[ch * 5 + j] * xs[p + j];
            c1s[ch][p] = (gp >= 0 && gp < 6000) ? siluf(a) : 0.f;
        }
    }
    __syncthreads();
    int pos = t0 + tid;
    if (pos < 6000) {
#pragma unroll
        for (int oc = 0; oc < 16; ++oc) {
            float a = wb2[oc];
#pragma unroll
            for (int ic = 0; ic < 4; ++ic)
#pragma unroll
                for (int j = 0; j < 5; ++j)
                    a += ws2[(oc * 4 + ic) * 5 + j] * c1s[ic][tid + j];
            c2[((size_t)n * 16 + oc) * 6000 + pos] = siluf(a);
        }
    }
}

// ---------------- im2col for conv3 (K padded 304 -> 320) ----------------
__global__ void k_im2col(const float* __restrict__ c2, float* __restrict__ A3) {
    int flat = blockIdx.x * 256 + threadIdx.x; // < 38400*40
    int m = flat / 40, c8 = flat % 40;
    int t = m >> 5, n = m & 31;
    float v[8];
#pragma unroll
    for (int e = 0; e < 8; ++e) {
        int k = c8 * 8 + e;
        float r = 0.f;
        if (k < 304) {
            int ic = k / 19, j = k % 19;
            int p = t * 5 - 9 + j;
            if (p >= 0 && p < 6000) r = c2[((size_t)n * 16 + ic) * 6000 + p];
        }
        v[e] = r;
    }
    float4 a, b;
    a.x = v[0]; a.y = v[1]; a.z = v[2]; a.w = v[3];
    b.x = v[4]; b.y = v[5]; b.z = v[6]; b.w = v[7];
    *(float4*)&A3[(size_t)m * 320 + c8 * 8] = a;
    *(float4*)&A3[(size_t)m * 320 + c8 * 8 + 4] = b;
}

// ---------------- MFMA GEMM: C[M,N] = act(A[M,K] @ B[N,K]^T + bias) ----------------
// A f32, split into hi/lo f16 at staging, 2 MFMAs per fragment (f32-accurate A).
// ACT: 0 none, 1 silu, 2 5*tanh
template <int ACT, typename OT>
__global__ __launch_bounds__(256, 2) void k_gemm(const float* __restrict__ A, const f16* __restrict__ B,
    const float* __restrict__ bias, OT* __restrict__ C, int K, int N) {
    const int tid = threadIdx.x;
    const int lane = tid & 63, wv = tid >> 6;
    const int wm = wv >> 1, wn = wv & 1;
    const int m0 = blockIdx.x * 128, n0 = blockIdx.y * 128;
    __shared__ __align__(16) f16 As[128 * 64];
    __shared__ __align__(16) f16 Al[128 * 64];
    __shared__ __align__(16) f16 Bs[128 * 64];
    f32x4 acc[4][4] = {};
    const int nk = K >> 6;
    for (int kb = 0; kb < nk; ++kb) {
#pragma unroll
        for (int i = 0; i < 4; ++i) {
            int cf = tid + i * 256;
            int row = cf >> 3, c = cf & 7;
            int sw = ((c ^ (row & 7)) << 3);
            *(f16x8*)&Bs[row * 64 + sw] = *(const f16x8*)&B[(size_t)(n0 + row) * K + kb * 64 + c * 8];
            float4 v0 = *(const float4*)&A[(size_t)(m0 + row) * K + kb * 64 + c * 8];
            float4 v1 = *(const float4*)&A[(size_t)(m0 + row) * K + kb * 64 + c * 8 + 4];
            float vv[8] = {v0.x, v0.y, v0.z, v0.w, v1.x, v1.y, v1.z, v1.w};
            f16x8 hi, lo;
#pragma unroll
            for (int e = 0; e < 8; ++e) {
                f16 h = (f16)vv[e];
                hi[e] = h;
                lo[e] = (f16)(vv[e] - (float)h);
            }
            *(f16x8*)&As[row * 64 + sw] = hi;
            *(f16x8*)&Al[row * 64 + sw] = lo;
        }
        __syncthreads();
#pragma unroll
        for (int kk = 0; kk < 2; ++kk) {
            f16x8 afh[4], afl[4], bf[4];
#pragma unroll
            for (int mi = 0; mi < 4; ++mi) {
                int row = wm * 64 + mi * 16 + (lane & 15);
                int c = kk * 4 + (lane >> 4);
                afh[mi] = *(const f16x8*)&As[row * 64 + ((c ^ (row & 7)) << 3)];
                afl[mi] = *(const f16x8*)&Al[row * 64 + ((c ^ (row & 7)) << 3)];
            }
#pragma unroll
            for (int ni = 0; ni < 4; ++ni) {
                int row = wn * 64 + ni * 16 + (lane & 15);
                int c = kk * 4 + (lane >> 4);
                bf[ni] = *(const f16x8*)&Bs[row * 64 + ((c ^ (row & 7)) << 3)];
            }
#pragma unroll
            for (int mi = 0; mi < 4; ++mi)
#pragma unroll
                for (int ni = 0; ni < 4; ++ni) {
                    acc[mi][ni] = __builtin_amdgcn_mfma_f32_16x16x32_f16(afh[mi], bf[ni], acc[mi][ni], 0, 0, 0);
                    acc[mi][ni] = __builtin_amdgcn_mfma_f32_16x16x32_f16(afl[mi], bf[ni], acc[mi][ni], 0, 0, 0);
                }
        }
        __syncthreads();
    }
#pragma unroll
    for (int mi = 0; mi < 4; ++mi) {
#pragma unroll
        for (int ni = 0; ni < 4; ++ni) {
            int gcol = n0 + wn * 64 + ni * 16 + (lane & 15);
            float bv = bias[gcol];
#pragma unroll
            for (int r = 0; r < 4; ++r) {
                int grow = m0 + wm * 64 + mi * 16 + (lane >> 4) * 4 + r;
                float v = acc[mi][ni][r] + bv;
                if (ACT == 1) v = v * (1.f / (1.f + __expf(-v)));
                else if (ACT == 2) v = 5.f - 10.f / (__expf(2.f * v) + 1.f);
                C[(size_t)grow * N + gcol] = (OT)v;
            }
        }
    }
}

// ---------------- LSTM recurrence: 32 teams (samples) x 8 WGs ----------------
// Team n's 8 blocks are all congruent mod 8 -> same XCD under round-robin
// dispatch -> per-step h exchange rides the XCD-local L2 (sc0, ~4x lower RT
// than L3). Producers dual-publish (L2 fast cell + L3 backup cell); pollers
// downgrade per-cell to the backup path after a capped miss window, so
// correctness never depends on the dispatch heuristic.
__global__ __launch_bounds__(256, 1) void k_rec(const float* __restrict__ G,
    const float* __restrict__ whh, float* __restrict__ Xout,
    unsigned* __restrict__ tupF, unsigned* __restrict__ tupB,
    int rev, unsigned tagbase) {
    const int tid = threadIdx.x;
    const int xcd = blockIdx.x & 7;
    const int idx = blockIdx.x >> 3;     // 0..31
    const int n = xcd * 4 + (idx >> 3);  // sample: teammates share one XCD
    const int w = idx & 7;               // 48-unit weight slice
    const int g3 = tid >> 2, kq = tid & 3;
    __shared__ __align__(16) float hlds[400]; // [4][100] padded quarters of 96
    __shared__ float gbuf[192];
    float4 wreg[3][24];
#pragma unroll
    for (int r = 0; r < 3; ++r) {
        int lr = 3 * g3 + r; // 0..191
        int gate = lr / 48, unit = lr % 48;
        const float* wp = whh + (size_t)(gate * HD + w * 48 + unit) * HD + kq * 96;
#pragma unroll
        for (int q = 0; q < 24; ++q) wreg[r][q] = *(const float4*)(wp + 4 * q);
    }
    if (tid < 100) {
        hlds[tid] = 0.f; hlds[100 + tid] = 0.f; hlds[200 + tid] = 0.f; hlds[300 + tid] = 0.f;
    }
    // producer setup (tid<24): units u0=2*tid, u0+1 of this WG
    float cstA = 0.f, cstB = 0.f;
    float* myH = nullptr;
    if (tid < 24) {
        int ug = w * 48 + 2 * tid;
        int c0 = ug / 96;
        myH = &hlds[c0 * 100 + (ug - c0 * 96)];
    }
    // poller setup (tid>=64): cell p covers 2 units of remote WG wj
    float* hq = nullptr; bool pollme = false;
    int cell = 0;
    if (tid >= 64) {
        int p = tid - 64;           // 0..179
        cell = (p < w * 24) ? p : (p + 24); // skip own WG's 24 cells
        pollme = (cell < 192);
        if (pollme) {
            int wj = cell / 24, jj = cell % 24;
            int u0 = wj * 48 + 2 * jj;
            int c0 = u0 / 96;
            hq = &hlds[c0 * 100 + (u0 - c0 * 96)];
        }
    }
    bool fastOK = true;
    // G for step 0 (producers)
    float pg[8];
    if (tid < 24) {
        int t0i = rev ? (T_LEN - 1) : 0;
        size_t gb = ((size_t)t0i * NB + n) * 1536 + w * 48 + 2 * tid;
#pragma unroll
        for (int g = 0; g < 4; ++g) {
            float2 gv = *(const float2*)&G[gb + g * 384];
            pg[2 * g] = gv.x; pg[2 * g + 1] = gv.y;
        }
    }
    __syncthreads();

    for (int s = 0; s < T_LEN; ++s) {
        // prefetch next-step G early; latency hides under the matvec
        float qv[8];
        const bool pref = (tid < 24) && (s + 1 < T_LEN);
        if (pref) {
            int tn = rev ? (T_LEN - 2 - s) : (s + 1);
            size_t gb = ((size_t)tn * NB + n) * 1536 + w * 48 + 2 * tid;
#pragma unroll
            for (int g = 0; g < 4; ++g) {
                float2 gv = *(const float2*)&G[gb + g * 384];
                qv[2 * g] = gv.x; qv[2 * g + 1] = gv.y;
            }
        }
        // ---- matvec: whh (regs) x h (LDS) ----
        float a0 = 0.f, a1 = 0.f, a2 = 0.f;
        const float4* hp = (const float4*)&hlds[kq * 100];
#pragma unroll
        for (int q = 0; q < 24; ++q) {
            float4 hv = hp[q];
            a0 = fmaf(wreg[0][q].x, hv.x, a0); a0 = fmaf(wreg[0][q].y, hv.y, a0);
            a0 = fmaf(wreg[0][q].z, hv.z, a0); a0 = fmaf(wreg[0][q].w, hv.w, a0);
            a1 = fmaf(wreg[1][q].x, hv.x, a1); a1 = fmaf(wreg[1][q].y, hv.y, a1);
            a1 = fmaf(wreg[1][q].z, hv.z, a1); a1 = fmaf(wreg[1][q].w, hv.w, a1);
            a2 = fmaf(wreg[2][q].x, hv.x, a2); a2 = fmaf(wreg[2][q].y, hv.y, a2);
            a2 = fmaf(wreg[2][q].z, hv.z, a2); a2 = fmaf(wreg[2][q].w, hv.w, a2);
        }
        a0 += __shfl_xor(a0, 1); a0 += __shfl_xor(a0, 2);
        a1 += __shfl_xor(a1, 1); a1 += __shfl_xor(a1, 2);
        a2 += __shfl_xor(a2, 1); a2 += __shfl_xor(a2, 2);
        if (kq == 0) {
            gbuf[3 * g3 + 0] = a0;
            gbuf[3 * g3 + 1] = a1;
            gbuf[3 * g3 + 2] = a2;
        }
        if (pref) {
            asm volatile("" : "+v"(qv[0]), "+v"(qv[1]), "+v"(qv[2]), "+v"(qv[3]),
                              "+v"(qv[4]), "+v"(qv[5]), "+v"(qv[6]), "+v"(qv[7]));
        }
        __syncthreads(); // B1: gbuf ready; all hlds reads of step s done
        const int slot = s & 1;
        const unsigned tag = tagbase + (unsigned)s + 1u;
        if (tid < 24) {
            const int u0 = 2 * tid;
            float iv0 = pg[0] + gbuf[u0],       iv1 = pg[1] + gbuf[u0 + 1];
            float fv0 = pg[2] + gbuf[48 + u0],  fv1 = pg[3] + gbuf[48 + u0 + 1];
            float gv0 = pg[4] + gbuf[96 + u0],  gv1 = pg[5] + gbuf[96 + u0 + 1];
            float ov0 = pg[6] + gbuf[144 + u0], ov1 = pg[7] + gbuf[144 + u0 + 1];
            cstA = sigf(fv0) * cstA + sigf(iv0) * tanhf_s(gv0);
            cstB = sigf(fv1) * cstB + sigf(iv1) * tanhf_s(gv1);
            float hv0 = sigf(ov0) * tanhf_s(cstA);
            float hv1 = sigf(ov1) * tanhf_s(cstB);
            int t = rev ? (T_LEN - 1 - s) : s;
            float2 xo; xo.x = hv0; xo.y = hv1;
            *(float2*)&Xout[((size_t)t * NB + n) * HD + w * 48 + u0] = xo;
            myH[0] = hv0; myH[1] = hv1; // own-WG hlds direct
            if (s + 1 < T_LEN) {
                u32x2 A, B;
                A[0] = __builtin_bit_cast(unsigned, hv0); A[1] = tag;
                B[0] = __builtin_bit_cast(unsigned, hv1); B[1] = tag;
                size_t coff = (((size_t)slot * NB + n) * 192 + w * 24 + tid) * 4;
                st_pkt2_l2(&tupF[coff], A, B);
                st_pkt2_sys(&tupB[coff], A, B);
            }
        } else if (pollme && s + 1 < T_LEN) {
            size_t coff = (((size_t)slot * NB + n) * 192 + cell) * 4;
            u32x2 A, B;
            bool got = false;
            if (fastOK) {
                const int cap = (s == 0) ? 20000 : 64;
                for (int it = 0; it < cap; ++it) {
                    ld_pkt2_l2(&tupF[coff], A, B);
                    if (A[1] == tag && B[1] == tag) { got = true; break; }
                }
                if (!got) fastOK = false; // downgrade this cell permanently
            }
            if (!got) {
                int it = 0;
                do { ld_pkt2_sys(&tupB[coff], A, B); }
                while ((A[1] != tag || B[1] != tag) && ++it < 2000000);
            }
            hq[0] = __builtin_bit_cast(float, A[0]);
            hq[1] = __builtin_bit_cast(float, B[0]);
        }
        if (pref) {
#pragma unroll
            for (int i = 0; i < 8; ++i) pg[i] = qv[i];
        }
        __syncthreads(); // B2: hlds for step s+1 complete
    }
}

// ---------------- CRF logZ ----------------
__global__ __launch_bounds__(256) void k_crf(const float* __restrict__ S,
    const int* __restrict__ idx, float* __restrict__ logz) {
    const int n = blockIdx.x, s = threadIdx.x;
    __shared__ float ash[256];
    __shared__ float bsh[256];
    int ix[5];
#pragma unroll
    for (int a = 0; a < 5; ++a) ix[a] = idx[s * 5 + a];
    float alpha = 0.f;
    float M[5];
#pragma unroll
    for (int a = 0; a < 5; ++a) M[a] = S[(size_t)n * 1280 + s * 5 + a];
    for (int t = 0; t < T_LEN; ++t) {
        ash[s] = alpha;
        __syncthreads();
        float av[5];
#pragma unroll
        for (int a = 0; a < 5; ++a) av[a] = ash[ix[a]] + M[a];
        if (t + 1 < T_LEN) {
#pragma unroll
            for (int a = 0; a < 5; ++a) M[a] = S[((size_t)(t + 1) * NB + n) * 1280 + s * 5 + a];
        }
        float mx = av[0];
#pragma unroll
        for (int a = 1; a < 5; ++a) mx = fmaxf(mx, av[a]);
        float sum = 0.f;
#pragma unroll
        for (int a = 0; a < 5; ++a) sum += __expf(av[a] - mx);
        alpha = mx + __logf(sum);
        __syncthreads();
    }
    ash[s] = alpha;
    __syncthreads();
    for (int off = 128; off > 0; off >>= 1) {
        if (s < off) ash[s] = fmaxf(ash[s], ash[s + off]);
        __syncthreads();
    }
    float mxv = ash[0];
    bsh[s] = __expf(alpha - mxv);
    __syncthreads();
    for (int off = 128; off > 0; off >>= 1) {
        if (s < off) bsh[s] += bsh[s + off];
        __syncthreads();
    }
    if (s == 0) logz[n] = mxv + __logf(bsh[0]);
}

// ---------------- subtract logz/T ----------------
__global__ void k_sub(float* __restrict__ out, const float* __restrict__ logz) {
    size_t i = (size_t)blockIdx.x * 256 + threadIdx.x; // one float4 each
    float4* p = (float4*)out + i;
    int nn = (int)((i / 320) & 31);
    float d = logz[nn] * (1.f / 1200.f);
    float4 v = *p;
    v.x -= d; v.y -= d; v.z -= d; v.w -= d;
    *p = v;
}

extern "C" void kernel_launch(void* const* d_in, const int* in_sizes, int n_in,
                              void* d_out, int out_size, void* d_ws, size_t ws_size,
                              hipStream_t stream) {
    (void)in_sizes; (void)n_in; (void)out_size; (void)ws_size;
    const float* x    = (const float*)d_in[0];
    const float* w1   = (const float*)d_in[1];
    const float* b1   = (const float*)d_in[2];
    const float* w2   = (const float*)d_in[3];
    const float* b2   = (const float*)d_in[4];
    const float* w3   = (const float*)d_in[5];
    const float* b3   = (const float*)d_in[6];
    const float* linw = (const float*)d_in[7];
    const float* linb = (const float*)d_in[8];
    const float* wih[5];
    const float* whh[5];
    const float* lb[5];
    for (int l = 0; l < 5; ++l) {
        wih[l] = (const float*)d_in[9 + 3 * l];
        whh[l] = (const float*)d_in[10 + 3 * l];
        lb[l]  = (const float*)d_in[11 + 3 * l];
    }
    const int* idx = (const int*)d_in[24];
    float* out = (float*)d_out;
    char* ws = (char*)d_ws;

    float* G32   = (float*)(ws + 0);            // 235,929,600
    float* A3f   = (float*)(ws + 0);            // 49,152,000 (overlaps G, used before)
    float* c2f   = (float*)(ws + 56000000);     // 12,288,000 (overlaps G, used before)
    float* Xa32  = (float*)(ws + 235929600);    // 58,982,400
    float* Xb32  = (float*)(ws + 294912000);    // 58,982,400
    f16* wihf    = (f16*)(ws + 353894400);      // 5,898,240
    f16* linwf   = (f16*)(ws + 359792640);      // 983,040
    f16* w3p     = (f16*)(ws + 360775680);      // 245,760 (dead after conv3 GEMM)
    float* logz  = (float*)(ws + 361021440);    // 128

    for (int l = 0; l < 5; ++l)
        k_cvt<<<dim3(2304), 256, 0, stream>>>(wih[l], wihf + (size_t)l * 589824, 589824);
    k_cvt<<<dim3(1920), 256, 0, stream>>>(linw, linwf, 491520);
    k_w3p<<<dim3(480), 256, 0, stream>>>(w3, w3p);
    k_conv12<<<dim3(12, 32), 512, 0, stream>>>(x, w1, b1, w2, b2, c2f);
    k_im2col<<<dim3(6000), 256, 0, stream>>>(c2f, A3f);
    k_gemm<1, float><<<dim3(300, 3), 256, 0, stream>>>(A3f, w3p, b3, Xa32, 320, 384);

    // Packet buffers live in the head of the CURRENT layer's input X buffer:
    // it is fully dead once k_gemm<0> has consumed it, and alternates with the
    // output buffer so no layer writes over its own live packets. Stale
    // same-tag packets from a previous graph replay are bit-identical by
    // determinism, hence harmless; all other leftovers fail the tag check.
    float* Xcur = Xa32;
    float* Xnxt = Xb32;
    for (int l = 0; l < 5; ++l) {
        k_gemm<0, float><<<dim3(300, 12), 256, 0, stream>>>(Xcur, wihf + (size_t)l * 589824, lb[l], G32, 384, 1536);
        unsigned* tupF = (unsigned*)Xcur;              // 196,608 B
        unsigned* tupB = (unsigned*)Xcur + 49152;      // 196,608 B
        k_rec<<<dim3(256), 256, 0, stream>>>(G32, whh[l], Xnxt, tupF, tupB,
                                             ((l & 1) == 0) ? 1 : 0, (unsigned)(l * 4096 + 1));
        float* tmp = Xcur; Xcur = Xnxt; Xnxt = tmp;
    }
    k_gemm<2, float><<<dim3(300, 10), 256, 0, stream>>>(Xcur, linwf, linb, out, 384, 1280);
    k_crf<<<dim3(32), 256, 0, stream>>>(out, idx, logz);
    k_sub<<<dim3(48000), 256, 0, stream>>>(out, logz);
}

// Round 11
// 20360.402 us; speedup vs baseline: 1.4767x; 1.4767x over previous
//
#include <hip/hip_runtime.h>
#include <cstdint>
#include <cstddef>

typedef _Float16 f16;
typedef _Float16 f16x8 __attribute__((ext_vector_type(8)));
typedef float f32x4 __attribute__((ext_vector_type(4)));
typedef unsigned u32x2 __attribute__((ext_vector_type(2)));
typedef unsigned long long u64;

#define T_LEN 1200
#define NB 32
#define HD 384

__device__ __forceinline__ float sigf(float x) { return 1.f / (1.f + __expf(-x)); }
__device__ __forceinline__ float tanhf_s(float x) {
    float ax = fabsf(x);
    float e = __expf(-2.f * ax);
    float r = (1.f - e) / (1.f + e);
    return copysignf(r, x);
}
__device__ __forceinline__ float siluf(float x) { return x * sigf(x); }

// Fast wire: sc0 = L1 bypass, served by the XCD-local L2 (coherent within XCD).
__device__ __forceinline__ void st_pkt2_l2(unsigned* p, u32x2 a, u32x2 b) {
    asm volatile("global_store_dwordx2 %0, %1, off sc0\n\t"
                 "global_store_dwordx2 %0, %2, off offset:8 sc0"
                 :: "v"(p), "v"(a), "v"(b) : "memory");
}
__device__ __forceinline__ void ld_pkt2_l2(const unsigned* p, u32x2& a, u32x2& b) {
    asm volatile("global_load_dwordx2 %0, %2, off sc0\n\t"
                 "global_load_dwordx2 %1, %2, off offset:8 sc0\n\t"
                 "s_waitcnt vmcnt(0)"
                 : "=&v"(a), "=&v"(b) : "v"(p) : "memory");
}
// Backup wire: sc0 sc1 = full bypass, device-wide visible (r6-proven).
__device__ __forceinline__ void st_pkt2_sys(unsigned* p, u32x2 a, u32x2 b) {
    asm volatile("global_store_dwordx2 %0, %1, off sc0 sc1\n\t"
                 "global_store_dwordx2 %0, %2, off offset:8 sc0 sc1"
                 :: "v"(p), "v"(a), "v"(b) : "memory");
}
__device__ __forceinline__ void ld_pkt2_sys(const unsigned* p, u32x2& a, u32x2& b) {
    asm volatile("global_load_dwordx2 %0, %2, off sc0 sc1\n\t"
                 "global_load_dwordx2 %1, %2, off offset:8 sc0 sc1\n\t"
                 "s_waitcnt vmcnt(0)"
                 : "=&v"(a), "=&v"(b) : "v"(p) : "memory");
}

// ---------------- small conversion kernels ----------------
__global__ void k_cvt(const float* __restrict__ src, f16* __restrict__ dst, int n) {
    int i = blockIdx.x * 256 + threadIdx.x;
    if (i < n) dst[i] = (f16)src[i];
}

__global__ void k_w3p(const float* __restrict__ w3, f16* __restrict__ dst) {
    int i = blockIdx.x * 256 + threadIdx.x; // 384*320
    if (i >= 384 * 320) return;
    int c = i / 320, k = i % 320;
    dst[i] = (f16)((k < 304) ? w3[c * 304 + k] : 0.f);
}

// ---------------- conv1 + conv2 fused (f32 out) ----------------
__global__ __launch_bounds__(512) void k_conv12(const float* __restrict__ x,
    const float* __restrict__ w1, const float* __restrict__ b1,
    const float* __restrict__ w2, const float* __restrict__ b2,
    float* __restrict__ c2) {
    const int tid = threadIdx.x;
    const int n = blockIdx.y;
    const int t0 = blockIdx.x * 512;
    __shared__ float xs[520];
    __shared__ float c1s[4][520];
    __shared__ float ws1[20], wb1[4], ws2[320], wb2[16];
    if (tid < 20) ws1[tid] = w1[tid];
    if (tid < 4) wb1[tid] = b1[tid];
    if (tid < 320) ws2[tid] = w2[tid];
    if (tid < 16) wb2[tid] = b2[tid];
    for (int q = tid; q < 520; q += 512) {
        int xi = t0 - 4 + q;
        xs[q] = (xi >= 0 && xi < 6000) ? x[(size_t)n * 6000 + xi] : 0.f;
    }
    __syncthreads();
    for (int p = tid; p < 516; p += 512) {
        int gp = t0 - 2 + p;
#pragma unroll
        for (int ch = 0; ch < 4; ++ch) {
            float a = wb1[ch];
#pragma unroll
            for (int j = 0; j < 5; ++j) a += ws1[ch * 5 + j] * xs[p + j];
            c1s[ch][p] = (gp >= 0 && gp < 6000) ? siluf(a) : 0.f;
        }
    }
    __syncthreads();
    int pos = t0 + tid;
    if (pos < 6000) {
#pragma unroll
        for (int oc = 0; oc < 16; ++oc) {
            float a = wb2[oc];
#pragma unroll
            for (int ic = 0; ic < 4; ++ic)
#pragma unroll
                for (int j = 0; j < 5; ++j)
                    a += ws2[(oc * 4 + ic) * 5 + j] * c1s[ic][tid + j];
            c2[((size_t)n * 16 + oc) * 6000 + pos] = siluf(a);
        }
    }
}

// ---------------- im2col for conv3 (K padded 304 -> 320) ----------------
__global__ void k_im2col(const float* __restrict__ c2, float* __restrict__ A3) {
    int flat = blockIdx.x * 256 + threadIdx.x; // < 38400*40
    int m = flat / 40, c8 = flat % 40;
    int t = m >> 5, n = m & 31;
    float v[8];
#pragma unroll
    for (int e = 0; e < 8; ++e) {
        int k = c8 * 8 + e;
        float r = 0.f;
        if (k < 304) {
            int ic = k / 19, j = k % 19;
            int p = t * 5 - 9 + j;
            if (p >= 0 && p < 6000) r = c2[((size_t)n * 16 + ic) * 6000 + p];
        }
        v[e] = r;
    }
    float4 a, b;
    a.x = v[0]; a.y = v[1]; a.z = v[2]; a.w = v[3];
    b.x = v[4]; b.y = v[5]; b.z = v[6]; b.w = v[7];
    *(float4*)&A3[(size_t)m * 320 + c8 * 8] = a;
    *(float4*)&A3[(size_t)m * 320 + c8 * 8 + 4] = b;
}

// ---------------- MFMA GEMM: C[M,N] = act(A[M,K] @ B[N,K]^T + bias) ----------------
template <int ACT, typename OT>
__global__ __launch_bounds__(256, 2) void k_gemm(const float* __restrict__ A, const f16* __restrict__ B,
    const float* __restrict__ bias, OT* __restrict__ C, int K, int N) {
    const int tid = threadIdx.x;
    const int lane = tid & 63, wv = tid >> 6;
    const int wm = wv >> 1, wn = wv & 1;
    const int m0 = blockIdx.x * 128, n0 = blockIdx.y * 128;
    __shared__ __align__(16) f16 As[128 * 64];
    __shared__ __align__(16) f16 Al[128 * 64];
    __shared__ __align__(16) f16 Bs[128 * 64];
    f32x4 acc[4][4] = {};
    const int nk = K >> 6;
    for (int kb = 0; kb < nk; ++kb) {
#pragma unroll
        for (int i = 0; i < 4; ++i) {
            int cf = tid + i * 256;
            int row = cf >> 3, c = cf & 7;
            int sw = ((c ^ (row & 7)) << 3);
            *(f16x8*)&Bs[row * 64 + sw] = *(const f16x8*)&B[(size_t)(n0 + row) * K + kb * 64 + c * 8];
            float4 v0 = *(const float4*)&A[(size_t)(m0 + row) * K + kb * 64 + c * 8];
            float4 v1 = *(const float4*)&A[(size_t)(m0 + row) * K + kb * 64 + c * 8 + 4];
            float vv[8] = {v0.x, v0.y, v0.z, v0.w, v1.x, v1.y, v1.z, v1.w};
            f16x8 hi, lo;
#pragma unroll
            for (int e = 0; e < 8; ++e) {
                f16 h = (f16)vv[e];
                hi[e] = h;
                lo[e] = (f16)(vv[e] - (float)h);
            }
            *(f16x8*)&As[row * 64 + sw] = hi;
            *(f16x8*)&Al[row * 64 + sw] = lo;
        }
        __syncthreads();
#pragma unroll
        for (int kk = 0; kk < 2; ++kk) {
            f16x8 afh[4], afl[4], bf[4];
#pragma unroll
            for (int mi = 0; mi < 4; ++mi) {
                int row = wm * 64 + mi * 16 + (lane & 15);
                int c = kk * 4 + (lane >> 4);
                afh[mi] = *(const f16x8*)&As[row * 64 + ((c ^ (row & 7)) << 3)];
                afl[mi] = *(const f16x8*)&Al[row * 64 + ((c ^ (row & 7)) << 3)];
            }
#pragma unroll
            for (int ni = 0; ni < 4; ++ni) {
                int row = wn * 64 + ni * 16 + (lane & 15);
                int c = kk * 4 + (lane >> 4);
                bf[ni] = *(const f16x8*)&Bs[row * 64 + ((c ^ (row & 7)) << 3)];
            }
#pragma unroll
            for (int mi = 0; mi < 4; ++mi)
#pragma unroll
                for (int ni = 0; ni < 4; ++ni) {
                    acc[mi][ni] = __builtin_amdgcn_mfma_f32_16x16x32_f16(afh[mi], bf[ni], acc[mi][ni], 0, 0, 0);
                    acc[mi][ni] = __builtin_amdgcn_mfma_f32_16x16x32_f16(afl[mi], bf[ni], acc[mi][ni], 0, 0, 0);
                }
        }
        __syncthreads();
    }
#pragma unroll
    for (int mi = 0; mi < 4; ++mi) {
#pragma unroll
        for (int ni = 0; ni < 4; ++ni) {
            int gcol = n0 + wn * 64 + ni * 16 + (lane & 15);
            float bv = bias[gcol];
#pragma unroll
            for (int r = 0; r < 4; ++r) {
                int grow = m0 + wm * 64 + mi * 16 + (lane >> 4) * 4 + r;
                float v = acc[mi][ni][r] + bv;
                if (ACT == 1) v = v * (1.f / (1.f + __expf(-v)));
                else if (ACT == 2) v = 5.f - 10.f / (__expf(2.f * v) + 1.f);
                C[(size_t)grow * N + gcol] = (OT)v;
            }
        }
    }
}

// ---------------- LSTM recurrence: 32 teams x 8 WGs, XCC_ID-verified ----------------
// Startup: every block reads HW_REG_XCC_ID, publishes it; all blocks compute an
// identical slot assignment placing each team's 8 WGs on ONE physical XCD.
// Verified teams use the XCD-local L2 wire (sc0); mixed teams (and adaptive
// fallback after repeated misses) use the r6-proven device wire (sc0 sc1).
__global__ __launch_bounds__(256, 1) void k_rec(const float* __restrict__ G,
    const float* __restrict__ whh, float* __restrict__ Xout,
    unsigned* __restrict__ tupF, unsigned* __restrict__ tupB,
    u64* __restrict__ xmap, int rev, unsigned tagbase) {
    const int tid = threadIdx.x;
    const int bid = blockIdx.x;
    __shared__ unsigned char xsh[256];
    __shared__ int s_n, s_w, s_fast;
    __shared__ __align__(16) float hlds[400]; // [4][100] padded quarters of 96
    __shared__ float gbuf[192];

    // ---- XCD discovery & deterministic team formation ----
    unsigned xid;
    asm volatile("s_getreg_b32 %0, hwreg(HW_REG_XCC_ID)" : "=s"(xid));
    xid &= 7u;
    const unsigned want = 0xA0000000u + tagbase;
    if (tid == 0)
        __hip_atomic_store(&xmap[bid], ((u64)want << 32) | (u64)xid,
                           __ATOMIC_RELAXED, __HIP_MEMORY_SCOPE_AGENT);
    {
        u64 v; int it = 0;
        do {
            v = __hip_atomic_load(&xmap[tid], __ATOMIC_RELAXED, __HIP_MEMORY_SCOPE_AGENT);
        } while ((unsigned)(v >> 32) != want && ++it < 4000000);
        xsh[tid] = (unsigned char)(v & 7u);
    }
    __syncthreads();
    if (tid == 0) {
        int tot[8] = {0, 0, 0, 0, 0, 0, 0, 0};
        for (int b = 0; b < 256; ++b) tot[xsh[b]]++;
        int c[8] = {0, 0, 0, 0, 0, 0, 0, 0};
        int slot = -1, myLi = -1, li = 0;
        for (int b = 0; b < 256; ++b) {
            int xb = xsh[b], r = c[xb]++;
            if (b == bid) { if (r < 32) slot = xb * 32 + r; else myLi = li; }
            if (r >= 32) li++;
        }
        if (slot < 0) {
            int h = 0;
            for (int s2 = 0; s2 < 256; ++s2) {
                int xb = s2 >> 5, r = s2 & 31;
                int capx = tot[xb] < 32 ? tot[xb] : 32;
                if (r >= capx) { if (h == myLi) { slot = s2; break; } h++; }
            }
        }
        int n = slot >> 3, w = slot & 7;
        int xb = n >> 2;
        int capx = tot[xb] < 32 ? tot[xb] : 32;
        s_n = n; s_w = w;
        s_fast = (capx >= 8 * (n & 3) + 8) ? 1 : 0;
    }
    __syncthreads();
    const int n = s_n, w = s_w;
    const bool fastT = (s_fast != 0);

    const int g3 = tid >> 2, kq = tid & 3;
    float4 wreg[3][24];
#pragma unroll
    for (int r = 0; r < 3; ++r) {
        int lr = 3 * g3 + r; // 0..191
        int gate = lr / 48, unit = lr % 48;
        const float* wp = whh + (size_t)(gate * HD + w * 48 + unit) * HD + kq * 96;
#pragma unroll
        for (int q = 0; q < 24; ++q) wreg[r][q] = *(const float4*)(wp + 4 * q);
    }
    if (tid < 100) {
        hlds[tid] = 0.f; hlds[100 + tid] = 0.f; hlds[200 + tid] = 0.f; hlds[300 + tid] = 0.f;
    }
    float cstA = 0.f, cstB = 0.f;
    float* myH = nullptr;
    if (tid < 24) {
        int ug = w * 48 + 2 * tid;
        int c0 = ug / 96;
        myH = &hlds[c0 * 100 + (ug - c0 * 96)];
    }
    float* hq = nullptr; bool pollme = false;
    int cell = 0;
    if (tid >= 64) {
        int p = tid - 64;                   // 0..191
        cell = (p < w * 24) ? p : (p + 24); // skip own WG's 24 cells
        pollme = (cell < 192);
        if (pollme) {
            int wj = cell / 24, jj = cell % 24;
            int u0 = wj * 48 + 2 * jj;
            int c0 = u0 / 96;
            hq = &hlds[c0 * 100 + (u0 - c0 * 96)];
        }
    }
    bool fastEn = fastT;
    int fmiss = 0;
    float pg[8];
    if (tid < 24) {
        int t0i = rev ? (T_LEN - 1) : 0;
        size_t gb = ((size_t)t0i * NB + n) * 1536 + w * 48 + 2 * tid;
#pragma unroll
        for (int g = 0; g < 4; ++g) {
            float2 gv = *(const float2*)&G[gb + g * 384];
            pg[2 * g] = gv.x; pg[2 * g + 1] = gv.y;
        }
    }
    __syncthreads();

    for (int s = 0; s < T_LEN; ++s) {
        float qv[8];
        const bool pref = (tid < 24) && (s + 1 < T_LEN);
        if (pref) {
            int tn = rev ? (T_LEN - 2 - s) : (s + 1);
            size_t gb = ((size_t)tn * NB + n) * 1536 + w * 48 + 2 * tid;
#pragma unroll
            for (int g = 0; g < 4; ++g) {
                float2 gv = *(const float2*)&G[gb + g * 384];
                qv[2 * g] = gv.x; qv[2 * g + 1] = gv.y;
            }
        }
        // ---- matvec: whh (regs) x h (LDS) ----
        float a0 = 0.f, a1 = 0.f, a2 = 0.f;
        const float4* hp = (const float4*)&hlds[kq * 100];
#pragma unroll
        for (int q = 0; q < 24; ++q) {
            float4 hv = hp[q];
            a0 = fmaf(wreg[0][q].x, hv.x, a0); a0 = fmaf(wreg[0][q].y, hv.y, a0);
            a0 = fmaf(wreg[0][q].z, hv.z, a0); a0 = fmaf(wreg[0][q].w, hv.w, a0);
            a1 = fmaf(wreg[1][q].x, hv.x, a1); a1 = fmaf(wreg[1][q].y, hv.y, a1);
            a1 = fmaf(wreg[1][q].z, hv.z, a1); a1 = fmaf(wreg[1][q].w, hv.w, a1);
            a2 = fmaf(wreg[2][q].x, hv.x, a2); a2 = fmaf(wreg[2][q].y, hv.y, a2);
            a2 = fmaf(wreg[2][q].z, hv.z, a2); a2 = fmaf(wreg[2][q].w, hv.w, a2);
        }
        a0 += __shfl_xor(a0, 1); a0 += __shfl_xor(a0, 2);
        a1 += __shfl_xor(a1, 1); a1 += __shfl_xor(a1, 2);
        a2 += __shfl_xor(a2, 1); a2 += __shfl_xor(a2, 2);
        if (kq == 0) {
            gbuf[3 * g3 + 0] = a0;
            gbuf[3 * g3 + 1] = a1;
            gbuf[3 * g3 + 2] = a2;
        }
        if (pref) {
            asm volatile("" : "+v"(qv[0]), "+v"(qv[1]), "+v"(qv[2]), "+v"(qv[3]),
                              "+v"(qv[4]), "+v"(qv[5]), "+v"(qv[6]), "+v"(qv[7]));
        }
        __syncthreads(); // B1
        const int slot = s & 1;
        const unsigned tag = tagbase + (unsigned)s + 1u;
        if (tid < 24) {
            const int u0 = 2 * tid;
            float iv0 = pg[0] + gbuf[u0],       iv1 = pg[1] + gbuf[u0 + 1];
            float fv0 = pg[2] + gbuf[48 + u0],  fv1 = pg[3] + gbuf[48 + u0 + 1];
            float gv0 = pg[4] + gbuf[96 + u0],  gv1 = pg[5] + gbuf[96 + u0 + 1];
            float ov0 = pg[6] + gbuf[144 + u0], ov1 = pg[7] + gbuf[144 + u0 + 1];
            cstA = sigf(fv0) * cstA + sigf(iv0) * tanhf_s(gv0);
            cstB = sigf(fv1) * cstB + sigf(iv1) * tanhf_s(gv1);
            float hv0 = sigf(ov0) * tanhf_s(cstA);
            float hv1 = sigf(ov1) * tanhf_s(cstB);
            int t = rev ? (T_LEN - 1 - s) : s;
            float2 xo; xo.x = hv0; xo.y = hv1;
            *(float2*)&Xout[((size_t)t * NB + n) * HD + w * 48 + u0] = xo;
            myH[0] = hv0; myH[1] = hv1;
            if (s + 1 < T_LEN) {
                u32x2 A, B;
                A[0] = __builtin_bit_cast(unsigned, hv0); A[1] = tag;
                B[0] = __builtin_bit_cast(unsigned, hv1); B[1] = tag;
                size_t coff = (((size_t)slot * NB + n) * 192 + w * 24 + tid) * 4;
                if (fastT) st_pkt2_l2(&tupF[coff], A, B);
                st_pkt2_sys(&tupB[coff], A, B);
            }
        } else if (pollme && s + 1 < T_LEN) {
            size_t coff = (((size_t)slot * NB + n) * 192 + cell) * 4;
            u32x2 A, B;
            bool got = false;
            if (fastEn) {
                for (int it = 0; it < 48; ++it) {
                    ld_pkt2_l2(&tupF[coff], A, B);
                    if (A[1] == tag && B[1] == tag) { got = true; break; }
                }
                if (!got && ++fmiss > 8) fastEn = false; // adaptive downgrade
            }
            if (!got) {
                int it = 0;
                do { ld_pkt2_sys(&tupB[coff], A, B); }
                while ((A[1] != tag || B[1] != tag) && ++it < 2000000);
            }
            hq[0] = __builtin_bit_cast(float, A[0]);
            hq[1] = __builtin_bit_cast(float, B[0]);
        }
        if (pref) {
#pragma unroll
            for (int i = 0; i < 8; ++i) pg[i] = qv[i];
        }
        __syncthreads(); // B2
    }
}

// ---------------- CRF logZ ----------------
__global__ __launch_bounds__(256) void k_crf(const float* __restrict__ S,
    const int* __restrict__ idx, float* __restrict__ logz) {
    const int n = blockIdx.x, s = threadIdx.x;
    __shared__ float ash[256];
    __shared__ float bsh[256];
    int ix[5];
#pragma unroll
    for (int a = 0; a < 5; ++a) ix[a] = idx[s * 5 + a];
    float alpha = 0.f;
    float M[5];
#pragma unroll
    for (int a = 0; a < 5; ++a) M[a] = S[(size_t)n * 1280 + s * 5 + a];
    for (int t = 0; t < T_LEN; ++t) {
        ash[s] = alpha;
        __syncthreads();
        float av[5];
#pragma unroll
        for (int a = 0; a < 5; ++a) av[a] = ash[ix[a]] + M[a];
        if (t + 1 < T_LEN) {
#pragma unroll
            for (int a = 0; a < 5; ++a) M[a] = S[((size_t)(t + 1) * NB + n) * 1280 + s * 5 + a];
        }
        float mx = av[0];
#pragma unroll
        for (int a = 1; a < 5; ++a) mx = fmaxf(mx, av[a]);
        float sum = 0.f;
#pragma unroll
        for (int a = 0; a < 5; ++a) sum += __expf(av[a] - mx);
        alpha = mx + __logf(sum);
        __syncthreads();
    }
    ash[s] = alpha;
    __syncthreads();
    for (int off = 128; off > 0; off >>= 1) {
        if (s < off) ash[s] = fmaxf(ash[s], ash[s + off]);
        __syncthreads();
    }
    float mxv = ash[0];
    bsh[s] = __expf(alpha - mxv);
    __syncthreads();
    for (int off = 128; off > 0; off >>= 1) {
        if (s < off) bsh[s] += bsh[s + off];
        __syncthreads();
    }
    if (s == 0) logz[n] = mxv + __logf(bsh[0]);
}

// ---------------- subtract logz/T ----------------
__global__ void k_sub(float* __restrict__ out, const float* __restrict__ logz) {
    size_t i = (size_t)blockIdx.x * 256 + threadIdx.x; // one float4 each
    float4* p = (float4*)out + i;
    int nn = (int)((i / 320) & 31);
    float d = logz[nn] * (1.f / 1200.f);
    float4 v = *p;
    v.x -= d; v.y -= d; v.z -= d; v.w -= d;
    *p = v;
}

extern "C" void kernel_launch(void* const* d_in, const int* in_sizes, int n_in,
                              void* d_out, int out_size, void* d_ws, size_t ws_size,
                              hipStream_t stream) {
    (void)in_sizes; (void)n_in; (void)out_size; (void)ws_size;
    const float* x    = (const float*)d_in[0];
    const float* w1   = (const float*)d_in[1];
    const float* b1   = (const float*)d_in[2];
    const float* w2   = (const float*)d_in[3];
    const float* b2   = (const float*)d_in[4];
    const float* w3   = (const float*)d_in[5];
    const float* b3   = (const float*)d_in[6];
    const float* linw = (const float*)d_in[7];
    const float* linb = (const float*)d_in[8];
    const float* wih[5];
    const float* whh[5];
    const float* lb[5];
    for (int l = 0; l < 5; ++l) {
        wih[l] = (const float*)d_in[9 + 3 * l];
        whh[l] = (const float*)d_in[10 + 3 * l];
        lb[l]  = (const float*)d_in[11 + 3 * l];
    }
    const int* idx = (const int*)d_in[24];
    float* out = (float*)d_out;
    char* ws = (char*)d_ws;

    float* G32   = (float*)(ws + 0);            // 235,929,600
    float* A3f   = (float*)(ws + 0);            // 49,152,000 (overlaps G, used before)
    float* c2f   = (float*)(ws + 56000000);     // 12,288,000 (overlaps G, used before)
    float* Xa32  = (float*)(ws + 235929600);    // 58,982,400
    float* Xb32  = (float*)(ws + 294912000);    // 58,982,400
    f16* wihf    = (f16*)(ws + 353894400);      // 5,898,240
    f16* linwf   = (f16*)(ws + 359792640);      // 983,040
    f16* w3p     = (f16*)(ws + 360775680);      // 245,760 (dead after conv3 GEMM)
    float* logz  = (float*)(ws + 361021440);    // 128
    u64* xmap    = (u64*)(ws + 361021568);      // 2,048

    for (int l = 0; l < 5; ++l)
        k_cvt<<<dim3(2304), 256, 0, stream>>>(wih[l], wihf + (size_t)l * 589824, 589824);
    k_cvt<<<dim3(1920), 256, 0, stream>>>(linw, linwf, 491520);
    k_w3p<<<dim3(480), 256, 0, stream>>>(w3, w3p);
    k_conv12<<<dim3(12, 32), 512, 0, stream>>>(x, w1, b1, w2, b2, c2f);
    k_im2col<<<dim3(6000), 256, 0, stream>>>(c2f, A3f);
    k_gemm<1, float><<<dim3(300, 3), 256, 0, stream>>>(A3f, w3p, b3, Xa32, 320, 384);

    // Packet buffers live in the head of the CURRENT layer's input X buffer
    // (fully dead once k_gemm<0> consumed it; alternates with the output
    // buffer). Stale same-tag packets across graph replays are bit-identical
    // by determinism; everything else fails the tag check. [r10-validated]
    float* Xcur = Xa32;
    float* Xnxt = Xb32;
    for (int l = 0; l < 5; ++l) {
        k_gemm<0, float><<<dim3(300, 12), 256, 0, stream>>>(Xcur, wihf + (size_t)l * 589824, lb[l], G32, 384, 1536);
        unsigned* tupF = (unsigned*)Xcur;              // 196,608 B
        unsigned* tupB = (unsigned*)Xcur + 49152;      // 196,608 B
        k_rec<<<dim3(256), 256, 0, stream>>>(G32, whh[l], Xnxt, tupF, tupB, xmap,
                                             ((l & 1) == 0) ? 1 : 0, (unsigned)(l * 4096 + 1));
        float* tmp = Xcur; Xcur = Xnxt; Xnxt = tmp;
    }
    k_gemm<2, float><<<dim3(300, 10), 256, 0, stream>>>(Xcur, linwf, linb, out, 384, 1280);
    k_crf<<<dim3(32), 256, 0, stream>>>(out, idx, logz);
    k_sub<<<dim3(48000), 256, 0, stream>>>(out, logz);
}

// Round 12
// 12382.150 us; speedup vs baseline: 2.4282x; 1.6443x over previous
//
#include <hip/hip_runtime.h>
#include <cstdint>
#include <cstddef>

typedef _Float16 f16;
typedef _Float16 f16x8 __attribute__((ext_vector_type(8)));
typedef float f32x4 __attribute__((ext_vector_type(4)));
typedef unsigned long long u64;

#define T_LEN 1200
#define NB 32
#define HD 384

__device__ __forceinline__ float sigf(float x) { return 1.f / (1.f + __expf(-x)); }
__device__ __forceinline__ float tanhf_s(float x) {
    float ax = fabsf(x);
    float e = __expf(-2.f * ax);
    float r = (1.f - e) / (1.f + e);
    return copysignf(r, x);
}
__device__ __forceinline__ float siluf(float x) { return x * sigf(x); }

// Device-visible 8B single-copy-atomic packet {h, tag} (r6-proven wire).
__device__ __forceinline__ u64 ld_pkt_sys(const u64* p) {
    u64 r;
    asm volatile("global_load_dwordx2 %0, %1, off sc0 sc1\n\ts_waitcnt vmcnt(0)"
                 : "=v"(r) : "v"(p) : "memory");
    return r;
}
__device__ __forceinline__ void st_pkt_sys(u64* p, u64 v) {
    asm volatile("global_store_dwordx2 %0, %1, off sc0 sc1" :: "v"(p), "v"(v) : "memory");
}

// ---------------- small conversion kernels ----------------
__global__ void k_cvt(const float* __restrict__ src, f16* __restrict__ dst, int n) {
    int i = blockIdx.x * 256 + threadIdx.x;
    if (i < n) dst[i] = (f16)src[i];
}

__global__ void k_w3p(const float* __restrict__ w3, f16* __restrict__ dst) {
    int i = blockIdx.x * 256 + threadIdx.x; // 384*320
    if (i >= 384 * 320) return;
    int c = i / 320, k = i % 320;
    dst[i] = (f16)((k < 304) ? w3[c * 304 + k] : 0.f);
}

// ---------------- conv1 + conv2 fused (f32 out) ----------------
__global__ __launch_bounds__(512) void k_conv12(const float* __restrict__ x,
    const float* __restrict__ w1, const float* __restrict__ b1,
    const float* __restrict__ w2, const float* __restrict__ b2,
    float* __restrict__ c2) {
    const int tid = threadIdx.x;
    const int n = blockIdx.y;
    const int t0 = blockIdx.x * 512;
    __shared__ float xs[520];
    __shared__ float c1s[4][520];
    __shared__ float ws1[20], wb1[4], ws2[320], wb2[16];
    if (tid < 20) ws1[tid] = w1[tid];
    if (tid < 4) wb1[tid] = b1[tid];
    if (tid < 320) ws2[tid] = w2[tid];
    if (tid < 16) wb2[tid] = b2[tid];
    for (int q = tid; q < 520; q += 512) {
        int xi = t0 - 4 + q;
        xs[q] = (xi >= 0 && xi < 6000) ? x[(size_t)n * 6000 + xi] : 0.f;
    }
    __syncthreads();
    for (int p = tid; p < 516; p += 512) {
        int gp = t0 - 2 + p;
#pragma unroll
        for (int ch = 0; ch < 4; ++ch) {
            float a = wb1[ch];
#pragma unroll
            for (int j = 0; j < 5; ++j) a += ws1[ch * 5 + j] * xs[p + j];
            c1s[ch][p] = (gp >= 0 && gp < 6000) ? siluf(a) : 0.f;
        }
    }
    __syncthreads();
    int pos = t0 + tid;
    if (pos < 6000) {
#pragma unroll
        for (int oc = 0; oc < 16; ++oc) {
            float a = wb2[oc];
#pragma unroll
            for (int ic = 0; ic < 4; ++ic)
#pragma unroll
                for (int j = 0; j < 5; ++j)
                    a += ws2[(oc * 4 + ic) * 5 + j] * c1s[ic][tid + j];
            c2[((size_t)n * 16 + oc) * 6000 + pos] = siluf(a);
        }
    }
}

// ---------------- im2col for conv3 (K padded 304 -> 320) ----------------
__global__ void k_im2col(const float* __restrict__ c2, float* __restrict__ A3) {
    int flat = blockIdx.x * 256 + threadIdx.x; // < 38400*40
    int m = flat / 40, c8 = flat % 40;
    int t = m >> 5, n = m & 31;
    float v[8];
#pragma unroll
    for (int e = 0; e < 8; ++e) {
        int k = c8 * 8 + e;
        float r = 0.f;
        if (k < 304) {
            int ic = k / 19, j = k % 19;
            int p = t * 5 - 9 + j;
            if (p >= 0 && p < 6000) r = c2[((size_t)n * 16 + ic) * 6000 + p];
        }
        v[e] = r;
    }
    float4 a, b;
    a.x = v[0]; a.y = v[1]; a.z = v[2]; a.w = v[3];
    b.x = v[4]; b.y = v[5]; b.z = v[6]; b.w = v[7];
    *(float4*)&A3[(size_t)m * 320 + c8 * 8] = a;
    *(float4*)&A3[(size_t)m * 320 + c8 * 8 + 4] = b;
}

// ---------------- MFMA GEMM: C[M,N] = act(A[M,K] @ B[N,K]^T + bias) ----------------
template <int ACT, typename OT>
__global__ __launch_bounds__(256, 2) void k_gemm(const float* __restrict__ A, const f16* __restrict__ B,
    const float* __restrict__ bias, OT* __restrict__ C, int K, int N) {
    const int tid = threadIdx.x;
    const int lane = tid & 63, wv = tid >> 6;
    const int wm = wv >> 1, wn = wv & 1;
    const int m0 = blockIdx.x * 128, n0 = blockIdx.y * 128;
    __shared__ __align__(16) f16 As[128 * 64];
    __shared__ __align__(16) f16 Al[128 * 64];
    __shared__ __align__(16) f16 Bs[128 * 64];
    f32x4 acc[4][4] = {};
    const int nk = K >> 6;
    for (int kb = 0; kb < nk; ++kb) {
#pragma unroll
        for (int i = 0; i < 4; ++i) {
            int cf = tid + i * 256;
            int row = cf >> 3, c = cf & 7;
            int sw = ((c ^ (row & 7)) << 3);
            *(f16x8*)&Bs[row * 64 + sw] = *(const f16x8*)&B[(size_t)(n0 + row) * K + kb * 64 + c * 8];
            float4 v0 = *(const float4*)&A[(size_t)(m0 + row) * K + kb * 64 + c * 8];
            float4 v1 = *(const float4*)&A[(size_t)(m0 + row) * K + kb * 64 + c * 8 + 4];
            float vv[8] = {v0.x, v0.y, v0.z, v0.w, v1.x, v1.y, v1.z, v1.w};
            f16x8 hi, lo;
#pragma unroll
            for (int e = 0; e < 8; ++e) {
                f16 h = (f16)vv[e];
                hi[e] = h;
                lo[e] = (f16)(vv[e] - (float)h);
            }
            *(f16x8*)&As[row * 64 + sw] = hi;
            *(f16x8*)&Al[row * 64 + sw] = lo;
        }
        __syncthreads();
#pragma unroll
        for (int kk = 0; kk < 2; ++kk) {
            f16x8 afh[4], afl[4], bf[4];
#pragma unroll
            for (int mi = 0; mi < 4; ++mi) {
                int row = wm * 64 + mi * 16 + (lane & 15);
                int c = kk * 4 + (lane >> 4);
                afh[mi] = *(const f16x8*)&As[row * 64 + ((c ^ (row & 7)) << 3)];
                afl[mi] = *(const f16x8*)&Al[row * 64 + ((c ^ (row & 7)) << 3)];
            }
#pragma unroll
            for (int ni = 0; ni < 4; ++ni) {
                int row = wn * 64 + ni * 16 + (lane & 15);
                int c = kk * 4 + (lane >> 4);
                bf[ni] = *(const f16x8*)&Bs[row * 64 + ((c ^ (row & 7)) << 3)];
            }
#pragma unroll
            for (int mi = 0; mi < 4; ++mi)
#pragma unroll
                for (int ni = 0; ni < 4; ++ni) {
                    acc[mi][ni] = __builtin_amdgcn_mfma_f32_16x16x32_f16(afh[mi], bf[ni], acc[mi][ni], 0, 0, 0);
                    acc[mi][ni] = __builtin_amdgcn_mfma_f32_16x16x32_f16(afl[mi], bf[ni], acc[mi][ni], 0, 0, 0);
                }
        }
        __syncthreads();
    }
#pragma unroll
    for (int mi = 0; mi < 4; ++mi) {
#pragma unroll
        for (int ni = 0; ni < 4; ++ni) {
            int gcol = n0 + wn * 64 + ni * 16 + (lane & 15);
            float bv = bias[gcol];
#pragma unroll
            for (int r = 0; r < 4; ++r) {
                int grow = m0 + wm * 64 + mi * 16 + (lane >> 4) * 4 + r;
                float v = acc[mi][ni][r] + bv;
                if (ACT == 1) v = v * (1.f / (1.f + __expf(-v)));
                else if (ACT == 2) v = 5.f - 10.f / (__expf(2.f * v) + 1.f);
                C[(size_t)grow * N + gcol] = (OT)v;
            }
        }
    }
}

// ---------------- LSTM recurrence: 32 teams (samples) x 8 WGs x 512 thr ----------------
// 512 threads/WG: 8-way K-split -> 144 weight floats/thread, resident in VGPRs
// (launch_bounds(512,2) -> 256-VGPR cap). Wire: r6-proven 8B {h,tag} sc0sc1
// packets, one per unit; 48 producers (1 unit each), 336 pollers.
__global__ __launch_bounds__(512, 2) void k_rec(const float* __restrict__ G,
    const float* __restrict__ whh, float* __restrict__ Xout,
    u64* __restrict__ tup, int rev, unsigned tagbase) {
    const int tid = threadIdx.x;
    const int n = blockIdx.x & 31, w = blockIdx.x >> 5;
    const int g3 = tid >> 3, kq = tid & 7;
    __shared__ __align__(16) float hlds[416]; // 8 chunks x 52 (48 used): kq start
    __shared__ float gbuf[192];               // banks {0,20,8,28,16,4,24,12} - conflict-free
    float4 wreg[3][12];
#pragma unroll
    for (int r = 0; r < 3; ++r) {
        int lr = 3 * g3 + r;             // 0..191
        int gate = lr / 48, unit = lr % 48;
        const float* wp = whh + (size_t)(gate * HD + w * 48 + unit) * HD + kq * 48;
#pragma unroll
        for (int q = 0; q < 12; ++q) wreg[r][q] = *(const float4*)(wp + 4 * q);
    }
    if (tid < 416) hlds[tid] = 0.f;
    float cst = 0.f;
    // poller setup: absolute unit uu of a remote WG
    const bool isP = (tid >= 64 && tid < 400);
    int uu = 0; float* hq = nullptr;
    if (isP) {
        int p = tid - 64;                 // 0..335
        uu = (p < w * 48) ? p : (p + 48); // skip own WG's 48 units
        hq = &hlds[(uu / 48) * 52 + (uu % 48)];
    }
    float pg0 = 0.f, pg1 = 0.f, pg2 = 0.f, pg3 = 0.f;
    if (tid < 48) {
        int t0 = rev ? (T_LEN - 1) : 0;
        size_t gb = ((size_t)t0 * NB + n) * 1536 + w * 48 + tid;
        pg0 = G[gb]; pg1 = G[gb + 384]; pg2 = G[gb + 768]; pg3 = G[gb + 1152];
    }
    __syncthreads();

    for (int s = 0; s < T_LEN; ++s) {
        float q0 = 0.f, q1 = 0.f, q2 = 0.f, q3 = 0.f;
        const bool pref = (tid < 48) && (s + 1 < T_LEN);
        if (pref) {
            int tn = rev ? (T_LEN - 2 - s) : (s + 1);
            size_t gb = ((size_t)tn * NB + n) * 1536 + w * 48 + tid;
            q0 = G[gb]; q1 = G[gb + 384]; q2 = G[gb + 768]; q3 = G[gb + 1152];
        }
        // ---- matvec: 3 rows x 48 cols per thread, weights in VGPRs ----
        float a0 = 0.f, a1 = 0.f, a2 = 0.f;
        const float4* hp = (const float4*)&hlds[kq * 52];
#pragma unroll
        for (int q = 0; q < 12; ++q) {
            float4 hv = hp[q];
            a0 = fmaf(wreg[0][q].x, hv.x, a0); a0 = fmaf(wreg[0][q].y, hv.y, a0);
            a0 = fmaf(wreg[0][q].z, hv.z, a0); a0 = fmaf(wreg[0][q].w, hv.w, a0);
            a1 = fmaf(wreg[1][q].x, hv.x, a1); a1 = fmaf(wreg[1][q].y, hv.y, a1);
            a1 = fmaf(wreg[1][q].z, hv.z, a1); a1 = fmaf(wreg[1][q].w, hv.w, a1);
            a2 = fmaf(wreg[2][q].x, hv.x, a2); a2 = fmaf(wreg[2][q].y, hv.y, a2);
            a2 = fmaf(wreg[2][q].z, hv.z, a2); a2 = fmaf(wreg[2][q].w, hv.w, a2);
        }
        a0 += __shfl_xor(a0, 1); a0 += __shfl_xor(a0, 2); a0 += __shfl_xor(a0, 4);
        a1 += __shfl_xor(a1, 1); a1 += __shfl_xor(a1, 2); a1 += __shfl_xor(a1, 4);
        a2 += __shfl_xor(a2, 1); a2 += __shfl_xor(a2, 2); a2 += __shfl_xor(a2, 4);
        if (kq == 0) {
            gbuf[3 * g3 + 0] = a0;
            gbuf[3 * g3 + 1] = a1;
            gbuf[3 * g3 + 2] = a2;
        }
        if (pref) {
            asm volatile("" : "+v"(q0), "+v"(q1), "+v"(q2), "+v"(q3));
        }
        __syncthreads(); // B1: gbuf ready; all hlds reads of step s done
        const int slot = s & 1;
        const unsigned tag = tagbase + (unsigned)s + 1u;
        if (tid < 48) {
            float iv = pg0 + gbuf[tid];
            float fv = pg1 + gbuf[48 + tid];
            float gv = pg2 + gbuf[96 + tid];
            float ov = pg3 + gbuf[144 + tid];
            cst = sigf(fv) * cst + sigf(iv) * tanhf_s(gv);
            float hv = sigf(ov) * tanhf_s(cst);
            int t = rev ? (T_LEN - 1 - s) : s;
            Xout[((size_t)t * NB + n) * HD + w * 48 + tid] = hv;
            hlds[w * 52 + tid] = hv; // own-WG hlds direct
            if (s + 1 < T_LEN)
                st_pkt_sys(&tup[((size_t)slot * NB + n) * 384 + w * 48 + tid],
                           ((u64)tag << 32) | (u64)__builtin_bit_cast(unsigned, hv));
        } else if (isP && s + 1 < T_LEN) {
            const u64* ta = &tup[((size_t)slot * NB + n) * 384 + uu];
            u64 v; int it = 0;
            do { v = ld_pkt_sys(ta); }
            while ((unsigned)(v >> 32) != tag && ++it < 2000000);
            hq[0] = __builtin_bit_cast(float, (unsigned)v);
        }
        if (pref) { pg0 = q0; pg1 = q1; pg2 = q2; pg3 = q3; }
        __syncthreads(); // B2: hlds for step s+1 complete
    }
}

// ---------------- CRF logZ ----------------
__global__ __launch_bounds__(256) void k_crf(const float* __restrict__ S,
    const int* __restrict__ idx, float* __restrict__ logz) {
    const int n = blockIdx.x, s = threadIdx.x;
    __shared__ float ash[256];
    __shared__ float bsh[256];
    int ix[5];
#pragma unroll
    for (int a = 0; a < 5; ++a) ix[a] = idx[s * 5 + a];
    float alpha = 0.f;
    float M[5];
#pragma unroll
    for (int a = 0; a < 5; ++a) M[a] = S[(size_t)n * 1280 + s * 5 + a];
    for (int t = 0; t < T_LEN; ++t) {
        ash[s] = alpha;
        __syncthreads();
        float av[5];
#pragma unroll
        for (int a = 0; a < 5; ++a) av[a] = ash[ix[a]] + M[a];
        if (t + 1 < T_LEN) {
#pragma unroll
            for (int a = 0; a < 5; ++a) M[a] = S[((size_t)(t + 1) * NB + n) * 1280 + s * 5 + a];
        }
        float mx = av[0];
#pragma unroll
        for (int a = 1; a < 5; ++a) mx = fmaxf(mx, av[a]);
        float sum = 0.f;
#pragma unroll
        for (int a = 0; a < 5; ++a) sum += __expf(av[a] - mx);
        alpha = mx + __logf(sum);
        __syncthreads();
    }
    ash[s] = alpha;
    __syncthreads();
    for (int off = 128; off > 0; off >>= 1) {
        if (s < off) ash[s] = fmaxf(ash[s], ash[s + off]);
        __syncthreads();
    }
    float mxv = ash[0];
    bsh[s] = __expf(alpha - mxv);
    __syncthreads();
    for (int off = 128; off > 0; off >>= 1) {
        if (s < off) bsh[s] += bsh[s + off];
        __syncthreads();
    }
    if (s == 0) logz[n] = mxv + __logf(bsh[0]);
}

// ---------------- subtract logz/T ----------------
__global__ void k_sub(float* __restrict__ out, const float* __restrict__ logz) {
    size_t i = (size_t)blockIdx.x * 256 + threadIdx.x; // one float4 each
    float4* p = (float4*)out + i;
    int nn = (int)((i / 320) & 31);
    float d = logz[nn] * (1.f / 1200.f);
    float4 v = *p;
    v.x -= d; v.y -= d; v.z -= d; v.w -= d;
    *p = v;
}

extern "C" void kernel_launch(void* const* d_in, const int* in_sizes, int n_in,
                              void* d_out, int out_size, void* d_ws, size_t ws_size,
                              hipStream_t stream) {
    (void)in_sizes; (void)n_in; (void)out_size; (void)ws_size;
    const float* x    = (const float*)d_in[0];
    const float* w1   = (const float*)d_in[1];
    const float* b1   = (const float*)d_in[2];
    const float* w2   = (const float*)d_in[3];
    const float* b2   = (const float*)d_in[4];
    const float* w3   = (const float*)d_in[5];
    const float* b3   = (const float*)d_in[6];
    const float* linw = (const float*)d_in[7];
    const float* linb = (const float*)d_in[8];
    const float* wih[5];
    const float* whh[5];
    const float* lb[5];
    for (int l = 0; l < 5; ++l) {
        wih[l] = (const float*)d_in[9 + 3 * l];
        whh[l] = (const float*)d_in[10 + 3 * l];
        lb[l]  = (const float*)d_in[11 + 3 * l];
    }
    const int* idx = (const int*)d_in[24];
    float* out = (float*)d_out;
    char* ws = (char*)d_ws;

    float* G32   = (float*)(ws + 0);            // 235,929,600
    float* A3f   = (float*)(ws + 0);            // 49,152,000 (overlaps G, used before)
    float* c2f   = (float*)(ws + 56000000);     // 12,288,000 (overlaps G, used before)
    float* Xa32  = (float*)(ws + 235929600);    // 58,982,400
    float* Xb32  = (float*)(ws + 294912000);    // 58,982,400
    f16* wihf    = (f16*)(ws + 353894400);      // 5,898,240
    f16* linwf   = (f16*)(ws + 359792640);      // 983,040
    f16* w3p     = (f16*)(ws + 360775680);      // 245,760 (dead after conv3 GEMM)
    float* logz  = (float*)(ws + 361021440);    // 128

    for (int l = 0; l < 5; ++l)
        k_cvt<<<dim3(2304), 256, 0, stream>>>(wih[l], wihf + (size_t)l * 589824, 589824);
    k_cvt<<<dim3(1920), 256, 0, stream>>>(linw, linwf, 491520);
    k_w3p<<<dim3(480), 256, 0, stream>>>(w3, w3p);
    k_conv12<<<dim3(12, 32), 512, 0, stream>>>(x, w1, b1, w2, b2, c2f);
    k_im2col<<<dim3(6000), 256, 0, stream>>>(c2f, A3f);
    k_gemm<1, float><<<dim3(300, 3), 256, 0, stream>>>(A3f, w3p, b3, Xa32, 320, 384);

    // Packet buffer lives in the head of the CURRENT layer's input X buffer
    // (fully dead once k_gemm<0> consumed it; alternates with the output
    // buffer). Stale same-tag packets across graph replays are bit-identical
    // by determinism; X-data leftovers cannot collide with tag values (small
    // ints = denormal bit patterns, unreachable under FTZ). [r10/r11-validated]
    float* Xcur = Xa32;
    float* Xnxt = Xb32;
    for (int l = 0; l < 5; ++l) {
        k_gemm<0, float><<<dim3(300, 12), 256, 0, stream>>>(Xcur, wihf + (size_t)l * 589824, lb[l], G32, 384, 1536);
        u64* tup = (u64*)Xcur; // 2 slots x 32 x 384 x 8B = 196,608 B
        k_rec<<<dim3(256), 512, 0, stream>>>(G32, whh[l], Xnxt, tup,
                                             ((l & 1) == 0) ? 1 : 0, (unsigned)(l * 4096 + 1));
        float* tmp = Xcur; Xcur = Xnxt; Xnxt = tmp;
    }
    k_gemm<2, float><<<dim3(300, 10), 256, 0, stream>>>(Xcur, linwf, linb, out, 384, 1280);
    k_crf<<<dim3(32), 256, 0, stream>>>(out, idx, logz);
    k_sub<<<dim3(48000), 256, 0, stream>>>(out, logz);
}

// Round 13
// 12340.596 us; speedup vs baseline: 2.4364x; 1.0034x over previous
//
#include <hip/hip_runtime.h>
#include <cstdint>
#include <cstddef>

typedef _Float16 f16;
typedef _Float16 f16x8 __attribute__((ext_vector_type(8)));
typedef float f32x4 __attribute__((ext_vector_type(4)));
typedef unsigned long long u64;

#define T_LEN 1200
#define NB 32
#define HD 384

__device__ __forceinline__ float sigf(float x) { return 1.f / (1.f + __expf(-x)); }
__device__ __forceinline__ float tanhf_s(float x) {
    float ax = fabsf(x);
    float e = __expf(-2.f * ax);
    float r = (1.f - e) / (1.f + e);
    return copysignf(r, x);
}
__device__ __forceinline__ float siluf(float x) { return x * sigf(x); }

// Device-visible 8B single-copy-atomic packet {h, tag} (r6-proven wire).
__device__ __forceinline__ u64 ld_pkt_sys(const u64* p) {
    u64 r;
    asm volatile("global_load_dwordx2 %0, %1, off sc0 sc1\n\ts_waitcnt vmcnt(0)"
                 : "=v"(r) : "v"(p) : "memory");
    return r;
}
__device__ __forceinline__ void st_pkt_sys(u64* p, u64 v) {
    asm volatile("global_store_dwordx2 %0, %1, off sc0 sc1" :: "v"(p), "v"(v) : "memory");
}

// ---------------- small conversion kernels ----------------
__global__ void k_cvt(const float* __restrict__ src, f16* __restrict__ dst, int n) {
    int i = blockIdx.x * 256 + threadIdx.x;
    if (i < n) dst[i] = (f16)src[i];
}

__global__ void k_w3p(const float* __restrict__ w3, f16* __restrict__ dst) {
    int i = blockIdx.x * 256 + threadIdx.x; // 384*320
    if (i >= 384 * 320) return;
    int c = i / 320, k = i % 320;
    dst[i] = (f16)((k < 304) ? w3[c * 304 + k] : 0.f);
}

// ---------------- conv1 + conv2 fused (f32 out) ----------------
__global__ __launch_bounds__(512) void k_conv12(const float* __restrict__ x,
    const float* __restrict__ w1, const float* __restrict__ b1,
    const float* __restrict__ w2, const float* __restrict__ b2,
    float* __restrict__ c2) {
    const int tid = threadIdx.x;
    const int n = blockIdx.y;
    const int t0 = blockIdx.x * 512;
    __shared__ float xs[520];
    __shared__ float c1s[4][520];
    __shared__ float ws1[20], wb1[4], ws2[320], wb2[16];
    if (tid < 20) ws1[tid] = w1[tid];
    if (tid < 4) wb1[tid] = b1[tid];
    if (tid < 320) ws2[tid] = w2[tid];
    if (tid < 16) wb2[tid] = b2[tid];
    for (int q = tid; q < 520; q += 512) {
        int xi = t0 - 4 + q;
        xs[q] = (xi >= 0 && xi < 6000) ? x[(size_t)n * 6000 + xi] : 0.f;
    }
    __syncthreads();
    for (int p = tid; p < 516; p += 512) {
        int gp = t0 - 2 + p;
#pragma unroll
        for (int ch = 0; ch < 4; ++ch) {
            float a = wb1[ch];
#pragma unroll
            for (int j = 0; j < 5; ++j) a += ws1[ch * 5 + j] * xs[p + j];
            c1s[ch][p] = (gp >= 0 && gp < 6000) ? siluf(a) : 0.f;
        }
    }
    __syncthreads();
    int pos = t0 + tid;
    if (pos < 6000) {
#pragma unroll
        for (int oc = 0; oc < 16; ++oc) {
            float a = wb2[oc];
#pragma unroll
            for (int ic = 0; ic < 4; ++ic)
#pragma unroll
                for (int j = 0; j < 5; ++j)
                    a += ws2[(oc * 4 + ic) * 5 + j] * c1s[ic][tid + j];
            c2[((size_t)n * 16 + oc) * 6000 + pos] = siluf(a);
        }
    }
}

// ---------------- im2col for conv3 (K padded 304 -> 320) ----------------
__global__ void k_im2col(const float* __restrict__ c2, float* __restrict__ A3) {
    int flat = blockIdx.x * 256 + threadIdx.x; // < 38400*40
    int m = flat / 40, c8 = flat % 40;
    int t = m >> 5, n = m & 31;
    float v[8];
#pragma unroll
    for (int e = 0; e < 8; ++e) {
        int k = c8 * 8 + e;
        float r = 0.f;
        if (k < 304) {
            int ic = k / 19, j = k % 19;
            int p = t * 5 - 9 + j;
            if (p >= 0 && p < 6000) r = c2[((size_t)n * 16 + ic) * 6000 + p];
        }
        v[e] = r;
    }
    float4 a, b;
    a.x = v[0]; a.y = v[1]; a.z = v[2]; a.w = v[3];
    b.x = v[4]; b.y = v[5]; b.z = v[6]; b.w = v[7];
    *(float4*)&A3[(size_t)m * 320 + c8 * 8] = a;
    *(float4*)&A3[(size_t)m * 320 + c8 * 8 + 4] = b;
}

// ---------------- MFMA GEMM: C[M,N] = act(A[M,K] @ B[N,K]^T + bias) ----------------
template <int ACT, typename OT>
__global__ __launch_bounds__(256, 2) void k_gemm(const float* __restrict__ A, const f16* __restrict__ B,
    const float* __restrict__ bias, OT* __restrict__ C, int K, int N) {
    const int tid = threadIdx.x;
    const int lane = tid & 63, wv = tid >> 6;
    const int wm = wv >> 1, wn = wv & 1;
    const int m0 = blockIdx.x * 128, n0 = blockIdx.y * 128;
    __shared__ __align__(16) f16 As[128 * 64];
    __shared__ __align__(16) f16 Al[128 * 64];
    __shared__ __align__(16) f16 Bs[128 * 64];
    f32x4 acc[4][4] = {};
    const int nk = K >> 6;
    for (int kb = 0; kb < nk; ++kb) {
#pragma unroll
        for (int i = 0; i < 4; ++i) {
            int cf = tid + i * 256;
            int row = cf >> 3, c = cf & 7;
            int sw = ((c ^ (row & 7)) << 3);
            *(f16x8*)&Bs[row * 64 + sw] = *(const f16x8*)&B[(size_t)(n0 + row) * K + kb * 64 + c * 8];
            float4 v0 = *(const float4*)&A[(size_t)(m0 + row) * K + kb * 64 + c * 8];
            float4 v1 = *(const float4*)&A[(size_t)(m0 + row) * K + kb * 64 + c * 8 + 4];
            float vv[8] = {v0.x, v0.y, v0.z, v0.w, v1.x, v1.y, v1.z, v1.w};
            f16x8 hi, lo;
#pragma unroll
            for (int e = 0; e < 8; ++e) {
                f16 h = (f16)vv[e];
                hi[e] = h;
                lo[e] = (f16)(vv[e] - (float)h);
            }
            *(f16x8*)&As[row * 64 + sw] = hi;
            *(f16x8*)&Al[row * 64 + sw] = lo;
        }
        __syncthreads();
#pragma unroll
        for (int kk = 0; kk < 2; ++kk) {
            f16x8 afh[4], afl[4], bf[4];
#pragma unroll
            for (int mi = 0; mi < 4; ++mi) {
                int row = wm * 64 + mi * 16 + (lane & 15);
                int c = kk * 4 + (lane >> 4);
                afh[mi] = *(const f16x8*)&As[row * 64 + ((c ^ (row & 7)) << 3)];
                afl[mi] = *(const f16x8*)&Al[row * 64 + ((c ^ (row & 7)) << 3)];
            }
#pragma unroll
            for (int ni = 0; ni < 4; ++ni) {
                int row = wn * 64 + ni * 16 + (lane & 15);
                int c = kk * 4 + (lane >> 4);
                bf[ni] = *(const f16x8*)&Bs[row * 64 + ((c ^ (row & 7)) << 3)];
            }
#pragma unroll
            for (int mi = 0; mi < 4; ++mi)
#pragma unroll
                for (int ni = 0; ni < 4; ++ni) {
                    acc[mi][ni] = __builtin_amdgcn_mfma_f32_16x16x32_f16(afh[mi], bf[ni], acc[mi][ni], 0, 0, 0);
                    acc[mi][ni] = __builtin_amdgcn_mfma_f32_16x16x32_f16(afl[mi], bf[ni], acc[mi][ni], 0, 0, 0);
                }
        }
        __syncthreads();
    }
#pragma unroll
    for (int mi = 0; mi < 4; ++mi) {
#pragma unroll
        for (int ni = 0; ni < 4; ++ni) {
            int gcol = n0 + wn * 64 + ni * 16 + (lane & 15);
            float bv = bias[gcol];
#pragma unroll
            for (int r = 0; r < 4; ++r) {
                int grow = m0 + wm * 64 + mi * 16 + (lane >> 4) * 4 + r;
                float v = acc[mi][ni][r] + bv;
                if (ACT == 1) v = v * (1.f / (1.f + __expf(-v)));
                else if (ACT == 2) v = 5.f - 10.f / (__expf(2.f * v) + 1.f);
                C[(size_t)grow * N + gcol] = (OT)v;
            }
        }
    }
}

// ---------------- LSTM recurrence: 32 teams (samples) x 8 WGs x 512 thr ----------------
// 512 threads/WG, 8-way K-split -> 144 weight floats/thread. waves_per_eu(2,2)
// pins the allocator's occupancy target at 2 waves/EU (256-VGPR budget) so the
// weights stay RESIDENT in VGPRs instead of being re-streamed from L2 each
// step (r12: VGPR=100 => rematerialized loads, ~9MB/XCD/step of L2 traffic).
__global__ __launch_bounds__(512)
__attribute__((amdgpu_waves_per_eu(2, 2)))
void k_rec(const float* __restrict__ G,
    const float* __restrict__ whh, float* __restrict__ Xout,
    u64* __restrict__ tup, int rev, unsigned tagbase) {
    const int tid = threadIdx.x;
    const int n = blockIdx.x & 31, w = blockIdx.x >> 5;
    const int g3 = tid >> 3, kq = tid & 7;
    __shared__ __align__(16) float hlds[416]; // 8 chunks x 52 (48 used): kq start
    __shared__ float gbuf[192];               // banks {0,20,8,28,16,4,24,12} - conflict-free
    float4 wreg[3][12];
#pragma unroll
    for (int r = 0; r < 3; ++r) {
        int lr = 3 * g3 + r;             // 0..191
        int gate = lr / 48, unit = lr % 48;
        const float* wp = whh + (size_t)(gate * HD + w * 48 + unit) * HD + kq * 48;
#pragma unroll
        for (int q = 0; q < 12; ++q) wreg[r][q] = *(const float4*)(wp + 4 * q);
    }
    if (tid < 416) hlds[tid] = 0.f;
    float cst = 0.f;
    // poller setup: absolute unit uu of a remote WG
    const bool isP = (tid >= 64 && tid < 400);
    int uu = 0; float* hq = nullptr;
    if (isP) {
        int p = tid - 64;                 // 0..335
        uu = (p < w * 48) ? p : (p + 48); // skip own WG's 48 units
        hq = &hlds[(uu / 48) * 52 + (uu % 48)];
    }
    float pg0 = 0.f, pg1 = 0.f, pg2 = 0.f, pg3 = 0.f;
    if (tid < 48) {
        int t0 = rev ? (T_LEN - 1) : 0;
        size_t gb = ((size_t)t0 * NB + n) * 1536 + w * 48 + tid;
        pg0 = G[gb]; pg1 = G[gb + 384]; pg2 = G[gb + 768]; pg3 = G[gb + 1152];
    }
    __syncthreads();

    for (int s = 0; s < T_LEN; ++s) {
        float q0 = 0.f, q1 = 0.f, q2 = 0.f, q3 = 0.f;
        const bool pref = (tid < 48) && (s + 1 < T_LEN);
        if (pref) {
            int tn = rev ? (T_LEN - 2 - s) : (s + 1);
            size_t gb = ((size_t)tn * NB + n) * 1536 + w * 48 + tid;
            q0 = G[gb]; q1 = G[gb + 384]; q2 = G[gb + 768]; q3 = G[gb + 1152];
        }
        // ---- matvec: 3 rows x 48 cols per thread, weights in VGPRs ----
        float a0 = 0.f, a1 = 0.f, a2 = 0.f;
        const float4* hp = (const float4*)&hlds[kq * 52];
#pragma unroll
        for (int q = 0; q < 12; ++q) {
            float4 hv = hp[q];
            a0 = fmaf(wreg[0][q].x, hv.x, a0); a0 = fmaf(wreg[0][q].y, hv.y, a0);
            a0 = fmaf(wreg[0][q].z, hv.z, a0); a0 = fmaf(wreg[0][q].w, hv.w, a0);
            a1 = fmaf(wreg[1][q].x, hv.x, a1); a1 = fmaf(wreg[1][q].y, hv.y, a1);
            a1 = fmaf(wreg[1][q].z, hv.z, a1); a1 = fmaf(wreg[1][q].w, hv.w, a1);
            a2 = fmaf(wreg[2][q].x, hv.x, a2); a2 = fmaf(wreg[2][q].y, hv.y, a2);
            a2 = fmaf(wreg[2][q].z, hv.z, a2); a2 = fmaf(wreg[2][q].w, hv.w, a2);
        }
        a0 += __shfl_xor(a0, 1); a0 += __shfl_xor(a0, 2); a0 += __shfl_xor(a0, 4);
        a1 += __shfl_xor(a1, 1); a1 += __shfl_xor(a1, 2); a1 += __shfl_xor(a1, 4);
        a2 += __shfl_xor(a2, 1); a2 += __shfl_xor(a2, 2); a2 += __shfl_xor(a2, 4);
        if (kq == 0) {
            gbuf[3 * g3 + 0] = a0;
            gbuf[3 * g3 + 1] = a1;
            gbuf[3 * g3 + 2] = a2;
        }
        if (pref) {
            asm volatile("" : "+v"(q0), "+v"(q1), "+v"(q2), "+v"(q3));
        }
        __syncthreads(); // B1: gbuf ready; all hlds reads of step s done
        const int slot = s & 1;
        const unsigned tag = tagbase + (unsigned)s + 1u;
        if (tid < 48) {
            float iv = pg0 + gbuf[tid];
            float fv = pg1 + gbuf[48 + tid];
            float gv = pg2 + gbuf[96 + tid];
            float ov = pg3 + gbuf[144 + tid];
            cst = sigf(fv) * cst + sigf(iv) * tanhf_s(gv);
            float hv = sigf(ov) * tanhf_s(cst);
            int t = rev ? (T_LEN - 1 - s) : s;
            Xout[((size_t)t * NB + n) * HD + w * 48 + tid] = hv;
            hlds[w * 52 + tid] = hv; // own-WG hlds direct
            if (s + 1 < T_LEN)
                st_pkt_sys(&tup[((size_t)slot * NB + n) * 384 + w * 48 + tid],
                           ((u64)tag << 32) | (u64)__builtin_bit_cast(unsigned, hv));
        } else if (isP && s + 1 < T_LEN) {
            const u64* ta = &tup[((size_t)slot * NB + n) * 384 + uu];
            u64 v; int it = 0;
            do { v = ld_pkt_sys(ta); }
            while ((unsigned)(v >> 32) != tag && ++it < 2000000);
            hq[0] = __builtin_bit_cast(float, (unsigned)v);
        }
        if (pref) { pg0 = q0; pg1 = q1; pg2 = q2; pg3 = q3; }
        __syncthreads(); // B2: hlds for step s+1 complete
    }
}

// ---------------- CRF logZ ----------------
__global__ __launch_bounds__(256) void k_crf(const float* __restrict__ S,
    const int* __restrict__ idx, float* __restrict__ logz) {
    const int n = blockIdx.x, s = threadIdx.x;
    __shared__ float ash[256];
    __shared__ float bsh[256];
    int ix[5];
#pragma unroll
    for (int a = 0; a < 5; ++a) ix[a] = idx[s * 5 + a];
    float alpha = 0.f;
    float M[5];
#pragma unroll
    for (int a = 0; a < 5; ++a) M[a] = S[(size_t)n * 1280 + s * 5 + a];
    for (int t = 0; t < T_LEN; ++t) {
        ash[s] = alpha;
        __syncthreads();
        float av[5];
#pragma unroll
        for (int a = 0; a < 5; ++a) av[a] = ash[ix[a]] + M[a];
        if (t + 1 < T_LEN) {
#pragma unroll
            for (int a = 0; a < 5; ++a) M[a] = S[((size_t)(t + 1) * NB + n) * 1280 + s * 5 + a];
        }
        float mx = av[0];
#pragma unroll
        for (int a = 1; a < 5; ++a) mx = fmaxf(mx, av[a]);
        float sum = 0.f;
#pragma unroll
        for (int a = 0; a < 5; ++a) sum += __expf(av[a] - mx);
        alpha = mx + __logf(sum);
        __syncthreads();
    }
    ash[s] = alpha;
    __syncthreads();
    for (int off = 128; off > 0; off >>= 1) {
        if (s < off) ash[s] = fmaxf(ash[s], ash[s + off]);
        __syncthreads();
    }
    float mxv = ash[0];
    bsh[s] = __expf(alpha - mxv);
    __syncthreads();
    for (int off = 128; off > 0; off >>= 1) {
        if (s < off) bsh[s] += bsh[s + off];
        __syncthreads();
    }
    if (s == 0) logz[n] = mxv + __logf(bsh[0]);
}

// ---------------- subtract logz/T ----------------
__global__ void k_sub(float* __restrict__ out, const float* __restrict__ logz) {
    size_t i = (size_t)blockIdx.x * 256 + threadIdx.x; // one float4 each
    float4* p = (float4*)out + i;
    int nn = (int)((i / 320) & 31);
    float d = logz[nn] * (1.f / 1200.f);
    float4 v = *p;
    v.x -= d; v.y -= d; v.z -= d; v.w -= d;
    *p = v;
}

extern "C" void kernel_launch(void* const* d_in, const int* in_sizes, int n_in,
                              void* d_out, int out_size, void* d_ws, size_t ws_size,
                              hipStream_t stream) {
    (void)in_sizes; (void)n_in; (void)out_size; (void)ws_size;
    const float* x    = (const float*)d_in[0];
    const float* w1   = (const float*)d_in[1];
    const float* b1   = (const float*)d_in[2];
    const float* w2   = (const float*)d_in[3];
    const float* b2   = (const float*)d_in[4];
    const float* w3   = (const float*)d_in[5];
    const float* b3   = (const float*)d_in[6];
    const float* linw = (const float*)d_in[7];
    const float* linb = (const float*)d_in[8];
    const float* wih[5];
    const float* whh[5];
    const float* lb[5];
    for (int l = 0; l < 5; ++l) {
        wih[l] = (const float*)d_in[9 + 3 * l];
        whh[l] = (const float*)d_in[10 + 3 * l];
        lb[l]  = (const float*)d_in[11 + 3 * l];
    }
    const int* idx = (const int*)d_in[24];
    float* out = (float*)d_out;
    char* ws = (char*)d_ws;

    float* G32   = (float*)(ws + 0);            // 235,929,600
    float* A3f   = (float*)(ws + 0);            // 49,152,000 (overlaps G, used before)
    float* c2f   = (float*)(ws + 56000000);     // 12,288,000 (overlaps G, used before)
    float* Xa32  = (float*)(ws + 235929600);    // 58,982,400
    float* Xb32  = (float*)(ws + 294912000);    // 58,982,400
    f16* wihf    = (f16*)(ws + 353894400);      // 5,898,240
    f16* linwf   = (f16*)(ws + 359792640);      // 983,040
    f16* w3p     = (f16*)(ws + 360775680);      // 245,760 (dead after conv3 GEMM)
    float* logz  = (float*)(ws + 361021440);    // 128

    for (int l = 0; l < 5; ++l)
        k_cvt<<<dim3(2304), 256, 0, stream>>>(wih[l], wihf + (size_t)l * 589824, 589824);
    k_cvt<<<dim3(1920), 256, 0, stream>>>(linw, linwf, 491520);
    k_w3p<<<dim3(480), 256, 0, stream>>>(w3, w3p);
    k_conv12<<<dim3(12, 32), 512, 0, stream>>>(x, w1, b1, w2, b2, c2f);
    k_im2col<<<dim3(6000), 256, 0, stream>>>(c2f, A3f);
    k_gemm<1, float><<<dim3(300, 3), 256, 0, stream>>>(A3f, w3p, b3, Xa32, 320, 384);

    // Packet buffer lives in the head of the CURRENT layer's input X buffer
    // (fully dead once k_gemm<0> consumed it; alternates with the output
    // buffer). Stale same-tag packets across graph replays are bit-identical
    // by determinism; X-data leftovers cannot collide with tag values (small
    // ints = denormal bit patterns, unreachable under FTZ). [r10/r11-validated]
    float* Xcur = Xa32;
    float* Xnxt = Xb32;
    for (int l = 0; l < 5; ++l) {
        k_gemm<0, float><<<dim3(300, 12), 256, 0, stream>>>(Xcur, wihf + (size_t)l * 589824, lb[l], G32, 384, 1536);
        u64* tup = (u64*)Xcur; // 2 slots x 32 x 384 x 8B = 196,608 B
        k_rec<<<dim3(256), 512, 0, stream>>>(G32, whh[l], Xnxt, tup,
                                             ((l & 1) == 0) ? 1 : 0, (unsigned)(l * 4096 + 1));
        float* tmp = Xcur; Xcur = Xnxt; Xnxt = tmp;
    }
    k_gemm<2, float><<<dim3(300, 10), 256, 0, stream>>>(Xcur, linwf, linb, out, 384, 1280);
    k_crf<<<dim3(32), 256, 0, stream>>>(out, idx, logz);
    k_sub<<<dim3(48000), 256, 0, stream>>>(out, logz);
}